// Round 8
// baseline (691.634 us; speedup 1.0000x reference)
//
#include <hip/hip_runtime.h>

#define TT 65536          // total tokens = 8 * 8192
#define HDIM 512
#define NE 4
#define SEQL 8192
#define TPW 8             // tokens per wave
#define TPB 32            // tokens per block (4 waves)
#define NBLK (TT / TPB)   // 2048 blocks = exactly 8 resident blocks/CU
#define EPS 1e-3f         // ~30x the fp32 split-dot error bound

// Wave-per-token (coalesced, R2/R3's verified structure) at 8 waves/SIMD:
// weights live in LDS ([e][j][lane] transposed -> conflict-free ds_read_b32,
// one vaddr + imm offsets) freeing 32 VGPRs so the kernel fits 64 VGPR
// (__launch_bounds__(256,8) -> 32 waves/CU, 2x R3's latency hiding).
// Aux loss fused: lane 0's ssum/cnt are ALREADY the wave's full totals
// (all lanes compute identical per-token values from the broadcast logits;
// R7's butterfly double-counted by 64x — the 409.9 failure). Device-scope
// atomicAdd into ws[64]; last block (counter ws[64]) finalizes.
__global__ __launch_bounds__(256, 8) void moe_gate_fused(
    const float* __restrict__ x, const float* __restrict__ w,
    float* __restrict__ out, float* __restrict__ ws)
{
  const int tid  = threadIdx.x;
  const int lane = tid & 63;
  const int wv   = tid >> 6;
  const int b0 = lane & 1;
  const int b1 = (lane >> 1) & 1;

  __shared__ float wlds[NE * 8 * 64];   // [e][j][lane], 8 KB

  // stage weights: wave wv = expert wv; lane's chunk = {4l..4l+3} u {256+4l..+3}
  {
    const float4 a = *(const float4*)(w + wv * HDIM + 4 * lane);
    const float4 b = *(const float4*)(w + wv * HDIM + 256 + 4 * lane);
    wlds[(wv * 8 + 0) * 64 + lane] = a.x;
    wlds[(wv * 8 + 1) * 64 + lane] = a.y;
    wlds[(wv * 8 + 2) * 64 + lane] = a.z;
    wlds[(wv * 8 + 3) * 64 + lane] = a.w;
    wlds[(wv * 8 + 4) * 64 + lane] = b.x;
    wlds[(wv * 8 + 5) * 64 + lane] = b.y;
    wlds[(wv * 8 + 6) * 64 + lane] = b.z;
    wlds[(wv * 8 + 7) * 64 + lane] = b.w;
  }
  __syncthreads();
  const float* wl = wlds + lane;        // single vaddr; (e*8+j)*64 folds to imm offset

  float ssum[NE] = {0.f, 0.f, 0.f, 0.f};
  float cnt[NE]  = {0.f, 0.f, 0.f, 0.f};

  const int t0 = blockIdx.x * TPB + wv * TPW;
  const float4* xp = (const float4*)x;
  const size_t base = (size_t)t0 * (HDIM / 4);

  float4 cA = xp[base + lane];          // floats 4l..4l+3
  float4 cB = xp[base + 64 + lane];     // floats 256+4l..+3

  for (int i = 0; i < TPW; ++i) {
    float4 nA, nB;
    if (i + 1 < TPW) {
      const size_t nb = base + (size_t)(i + 1) * (HDIM / 4);
      nA = xp[nb + lane];
      nB = xp[nb + 64 + lane];
    }

    // per-lane fp32 partials; weights from LDS (32 conflict-free b32 reads)
    float pe[NE];
#pragma unroll
    for (int e = 0; e < NE; ++e) {
      float s = cA.x * wl[(e * 8 + 0) * 64];
      s = fmaf(cA.y, wl[(e * 8 + 1) * 64], s);
      s = fmaf(cA.z, wl[(e * 8 + 2) * 64], s);
      s = fmaf(cA.w, wl[(e * 8 + 3) * 64], s);
      s = fmaf(cB.x, wl[(e * 8 + 4) * 64], s);
      s = fmaf(cB.y, wl[(e * 8 + 5) * 64], s);
      s = fmaf(cB.z, wl[(e * 8 + 6) * 64], s);
      s = fmaf(cB.w, wl[(e * 8 + 7) * 64], s);
      pe[e] = s;
    }

    // reduce-scatter (masks 1,2) -> tree (4..32) -> allgather (1,2,3)  [R3-verified]
    const float s0 = (b0 ? pe[2] : pe[0]) + __shfl_xor(b0 ? pe[0] : pe[2], 1, 64);
    const float s1 = (b0 ? pe[3] : pe[1]) + __shfl_xor(b0 ? pe[1] : pe[3], 1, 64);
    float v = (b1 ? s1 : s0) + __shfl_xor(b1 ? s0 : s1, 2, 64);
    v += __shfl_xor(v, 4, 64);
    v += __shfl_xor(v, 8, 64);
    v += __shfl_xor(v, 16, 64);
    v += __shfl_xor(v, 32, 64);
    const float T2 = __shfl_xor(v, 1, 64);
    const float T1 = __shfl_xor(v, 2, 64);
    const float T3 = __shfl_xor(v, 3, 64);

    float acc[NE];
    acc[0] = b0 ? (b1 ? T3 : T2) : (b1 ? T1 : v);
    acc[1] = b0 ? (b1 ? T2 : T3) : (b1 ? v  : T1);
    acc[2] = b0 ? (b1 ? T1 : v)  : (b1 ? T3 : T2);
    acc[3] = b0 ? (b1 ? v  : T1) : (b1 ? T2 : T3);

    // top-1/2/3; strict '>' ascending = lowest-index tie-break
    int i0 = 0; float v0 = acc[0];
#pragma unroll
    for (int e = 1; e < NE; ++e) { if (acc[e] > v0) { v0 = acc[e]; i0 = e; } }
    int i1 = -1; float v1 = -3.4e38f;
#pragma unroll
    for (int e = 0; e < NE; ++e) { if (e != i0 && acc[e] > v1) { v1 = acc[e]; i1 = e; } }
    float v2 = -3.4e38f;
#pragma unroll
    for (int e = 0; e < NE; ++e) { if (e != i0 && e != i1 && acc[e] > v2) v2 = acc[e]; }

    // rare fp64 recompute on near-ties (wave-uniform; LDS weights are exact copies)
    const int risky = ((v0 - v1) < EPS) | ((v1 - v2) < EPS);
    if (__builtin_amdgcn_readfirstlane(risky)) {
      double dd[NE];
#pragma unroll
      for (int e = 0; e < NE; ++e) {
        double a = (double)cA.x * (double)wl[(e * 8 + 0) * 64];
        a += (double)cA.y * (double)wl[(e * 8 + 1) * 64];
        a += (double)cA.z * (double)wl[(e * 8 + 2) * 64];
        a += (double)cA.w * (double)wl[(e * 8 + 3) * 64];
        a += (double)cB.x * (double)wl[(e * 8 + 4) * 64];
        a += (double)cB.y * (double)wl[(e * 8 + 5) * 64];
        a += (double)cB.z * (double)wl[(e * 8 + 6) * 64];
        a += (double)cB.w * (double)wl[(e * 8 + 7) * 64];
#pragma unroll
        for (int m = 1; m < 64; m <<= 1) a += __shfl_xor(a, m, 64);
        dd[e] = a;
      }
      i0 = 0; double u0d = dd[0];
#pragma unroll
      for (int e = 1; e < NE; ++e) { if (dd[e] > u0d) { u0d = dd[e]; i0 = e; } }
      i1 = -1; double u1d = -1.0e300;
#pragma unroll
      for (int e = 0; e < NE; ++e) { if (e != i0 && dd[e] > u1d) { u1d = dd[e]; i1 = e; } }
#pragma unroll
      for (int e = 0; e < NE; ++e) acc[e] = (float)dd[e];
      v0 = (float)u0d;
    }

    // softmax (fp32)
    float u[NE]; float psum = 0.f;
#pragma unroll
    for (int e = 0; e < NE; ++e) { u[e] = __expf(acc[e] - v0); psum += u[e]; }
    const float inv = 1.0f / psum;
#pragma unroll
    for (int e = 0; e < NE; ++e) {
      ssum[e] += u[e] * inv;
      cnt[e] += ((e == i0) ? 1.f : 0.f) + ((e == i1) ? 1.f : 0.f);
    }

    const float ua = (i0 == 0) ? u[0] : (i0 == 1) ? u[1] : (i0 == 2) ? u[2] : u[3];
    const float ub = (i1 == 0) ? u[0] : (i1 == 1) ? u[1] : (i1 == 2) ? u[2] : u[3];
    const float denom = ua + ub + 1e-20f * psum;   // == (p0+p1+1e-20)*psum
    const float wt0 = ua / denom, wt1 = ub / denom;

    if (lane == 0) {
      const int t = t0 + i;
      float2 idx2 = {(float)i0, (float)i1};
      float2 wt2  = {wt0, wt1};
      *(float2*)(out + 2 * t) = idx2;
      *(float2*)(out + 2 * TT + 2 * t) = wt2;
    }
    cA = nA; cB = nB;
  }

  // fused aux: lane 0's ssum/cnt ARE the wave totals (all lanes identical) —
  // NO reduction here (R7 bug: butterfly double-counted by 64x).
  if (lane == 0) {
    const int batch = blockIdx.x >> 8;     // 256 blocks per batch
#pragma unroll
    for (int k = 0; k < NE; ++k) {
      atomicAdd(&ws[batch * 8 + k], ssum[k]);
      atomicAdd(&ws[batch * 8 + 4 + k], cnt[k]);
    }
    __threadfence();
  }
  __syncthreads();

  // last block finalizes aux_loss (counter at ws[64], zeroed per launch)
  if (wv == 0) {
    unsigned old = 0;
    if (lane == 0) old = atomicAdd((unsigned*)(ws + 64), 1u);
    old = __shfl((int)old, 0, 64);
    if (old == NBLK - 1) {
      const float val = atomicAdd(&ws[lane], 0.0f);   // fresh device-scope read
      const float oth = __shfl_xor(val, 4, 64);
      // lanes with (lane&4)==0: lane = b*8+e -> val=ssum(b,e), oth=cnt(b,e)
      float term = ((lane & 4) == 0) ? (oth / 4096.0f) * (val / 8192.0f) : 0.f;
#pragma unroll
      for (int m = 1; m < 64; m <<= 1) term += __shfl_xor(term, m, 64);
      if (lane == 0) out[4 * TT] = 0.1f * term / 8.0f;
    }
  }
}

extern "C" void kernel_launch(void* const* d_in, const int* in_sizes, int n_in,
                              void* d_out, int out_size, void* d_ws, size_t ws_size,
                              hipStream_t stream) {
  const float* x = (const float*)d_in[0];   // [8,8192,512] fp32
  const float* w = (const float*)d_in[1];   // [4,512] fp32
  float* out = (float*)d_out;               // idx[131072] | weight[131072] | aux[1]
  float* ws  = (float*)d_ws;                // [64] accum + [1] counter

  hipMemsetAsync(ws, 0, 512, stream);
  moe_gate_fused<<<NBLK, 256, 0, stream>>>(x, w, out, ws);
}

// Round 9
// 633.984 us; speedup vs baseline: 1.0909x; 1.0909x over previous
//
#include <hip/hip_runtime.h>

#define TT 65536          // total tokens = 8 * 8192
#define HDIM 512
#define NE 4
#define SEQL 8192
#define TPW 8             // tokens per wave
#define TPB 32            // tokens per block (4 waves)
#define NBLK (TT / TPB)   // 2048 blocks = 8 resident blocks/CU at 64 VGPR
#define EPS 1e-3f         // ~30x the fp32 split-dot error bound

// Wave-per-token at 8 waves/SIMD (64-VGPR budget). R8's 19x regression was
// hot-loop scratch spill (WRITE_SIZE 80MB) caused by the in-loop fp64
// fallback's register peak under launch_bounds(256,8). Fix: hot loop is
// PURE fp32 (risky tokens only set a bitmask); fp64 re-dot runs post-loop
// on flagged tokens (~0.2%), re-reading x from global (L3-warm) and
// overwriting out. Weights in LDS as float4 -> 8 ds_read_b128/token.
// Aux: lane0 partials (wave totals already) -> atomicAdd ws, last block
// finalizes (R8-verified).
__global__ __launch_bounds__(256, 8) void moe_gate_fused(
    const float* __restrict__ x, const float* __restrict__ w,
    float* __restrict__ out, float* __restrict__ ws)
{
  const int tid  = threadIdx.x;
  const int lane = tid & 63;
  const int wv   = tid >> 6;
  const int b0 = lane & 1;
  const int b1 = (lane >> 1) & 1;

  __shared__ float4 wlds[NE * 2 * 64];   // [e][half][lane], 8 KB

  // stage weights: wave wv = expert wv; lane's chunk = {4l..4l+3} u {256+4l..+3}
  {
    const float4 a = *(const float4*)(w + wv * HDIM + 4 * lane);
    const float4 b = *(const float4*)(w + wv * HDIM + 256 + 4 * lane);
    wlds[(wv * 2 + 0) * 64 + lane] = a;
    wlds[(wv * 2 + 1) * 64 + lane] = b;
  }
  __syncthreads();
  const float4* wl = wlds + lane;        // single vaddr; (e*2+h)*64 folds to imm offset

  float ssum[NE] = {0.f, 0.f, 0.f, 0.f};
  float cnt[NE]  = {0.f, 0.f, 0.f, 0.f};
  unsigned riskmask = 0u;

  const int t0 = blockIdx.x * TPB + wv * TPW;
  const float4* xp = (const float4*)x;
  const size_t base = (size_t)t0 * (HDIM / 4);

  float4 cA = xp[base + lane];          // floats 4l..4l+3
  float4 cB = xp[base + 64 + lane];     // floats 256+4l..+3

  for (int i = 0; i < TPW; ++i) {
    float4 nA, nB;
    if (i + 1 < TPW) {
      const size_t nb = base + (size_t)(i + 1) * (HDIM / 4);
      nA = xp[nb + lane];
      nB = xp[nb + 64 + lane];
    }

    // per-lane fp32 partials; weights via 8 conflict-free ds_read_b128
    float pe[NE];
#pragma unroll
    for (int e = 0; e < NE; ++e) {
      const float4 qa = wl[(e * 2 + 0) * 64];
      const float4 qb = wl[(e * 2 + 1) * 64];
      float s = cA.x * qa.x;
      s = fmaf(cA.y, qa.y, s);
      s = fmaf(cA.z, qa.z, s);
      s = fmaf(cA.w, qa.w, s);
      s = fmaf(cB.x, qb.x, s);
      s = fmaf(cB.y, qb.y, s);
      s = fmaf(cB.z, qb.z, s);
      s = fmaf(cB.w, qb.w, s);
      pe[e] = s;
    }

    // reduce-scatter (masks 1,2) -> tree (4..32) -> allgather (1,2,3)  [R3-verified]
    const float s0 = (b0 ? pe[2] : pe[0]) + __shfl_xor(b0 ? pe[0] : pe[2], 1, 64);
    const float s1 = (b0 ? pe[3] : pe[1]) + __shfl_xor(b0 ? pe[1] : pe[3], 1, 64);
    float v = (b1 ? s1 : s0) + __shfl_xor(b1 ? s0 : s1, 2, 64);
    v += __shfl_xor(v, 4, 64);
    v += __shfl_xor(v, 8, 64);
    v += __shfl_xor(v, 16, 64);
    v += __shfl_xor(v, 32, 64);
    const float T2 = __shfl_xor(v, 1, 64);
    const float T1 = __shfl_xor(v, 2, 64);
    const float T3 = __shfl_xor(v, 3, 64);

    float acc[NE];
    acc[0] = b0 ? (b1 ? T3 : T2) : (b1 ? T1 : v);
    acc[1] = b0 ? (b1 ? T2 : T3) : (b1 ? v  : T1);
    acc[2] = b0 ? (b1 ? T1 : v)  : (b1 ? T3 : T2);
    acc[3] = b0 ? (b1 ? v  : T1) : (b1 ? T2 : T3);

    // top-1/2/3; strict '>' ascending = lowest-index tie-break
    int i0 = 0; float v0 = acc[0];
#pragma unroll
    for (int e = 1; e < NE; ++e) { if (acc[e] > v0) { v0 = acc[e]; i0 = e; } }
    int i1 = -1; float v1 = -3.4e38f;
#pragma unroll
    for (int e = 0; e < NE; ++e) { if (e != i0 && acc[e] > v1) { v1 = acc[e]; i1 = e; } }
    float v2 = -3.4e38f;
#pragma unroll
    for (int e = 0; e < NE; ++e) { if (e != i0 && e != i1 && acc[e] > v2) v2 = acc[e]; }

    // near-tie? just flag it (fp64 handled POST-LOOP; keeps hot loop spill-free)
    const int risky = ((v0 - v1) < EPS) | ((v1 - v2) < EPS);
    riskmask |= ((unsigned)__builtin_amdgcn_readfirstlane(risky)) << i;

    // softmax (fp32)
    float u[NE]; float psum = 0.f;
#pragma unroll
    for (int e = 0; e < NE; ++e) { u[e] = __expf(acc[e] - v0); psum += u[e]; }
    const float inv = 1.0f / psum;
#pragma unroll
    for (int e = 0; e < NE; ++e) {
      ssum[e] += u[e] * inv;
      cnt[e] += ((e == i0) ? 1.f : 0.f) + ((e == i1) ? 1.f : 0.f);
    }

    const float ua = (i0 == 0) ? u[0] : (i0 == 1) ? u[1] : (i0 == 2) ? u[2] : u[3];
    const float ub = (i1 == 0) ? u[0] : (i1 == 1) ? u[1] : (i1 == 2) ? u[2] : u[3];
    const float denom = ua + ub + 1e-20f * psum;   // == (p0+p1+1e-20)*psum
    const float wt0 = ua / denom, wt1 = ub / denom;

    if (lane == 0) {
      const int t = t0 + i;
      float2 idx2 = {(float)i0, (float)i1};
      float2 wt2  = {wt0, wt1};
      *(float2*)(out + 2 * t) = idx2;
      *(float2*)(out + 2 * TT + 2 * t) = wt2;
    }
    cA = nA; cB = nB;
  }

  // fused aux: lane 0's ssum/cnt ARE the wave totals (all lanes identical)
  if (lane == 0) {
    const int batch = blockIdx.x >> 8;     // 256 blocks per batch
#pragma unroll
    for (int k = 0; k < NE; ++k) {
      atomicAdd(&ws[batch * 8 + k], ssum[k]);
      atomicAdd(&ws[batch * 8 + 4 + k], cnt[k]);
    }
    __threadfence();
  }

  // post-loop fp64 fixup of flagged tokens (~0.2% of waves enter)
  while (riskmask) {
    const int i = __builtin_ctz(riskmask);
    riskmask &= riskmask - 1;
    const size_t rb = base + (size_t)i * (HDIM / 4);
    const float4 rA = xp[rb + lane];
    const float4 rB = xp[rb + 64 + lane];
    double dd[NE];
#pragma unroll
    for (int e = 0; e < NE; ++e) {
      const float4 qa = wl[(e * 2 + 0) * 64];
      const float4 qb = wl[(e * 2 + 1) * 64];
      double a = (double)rA.x * (double)qa.x;
      a += (double)rA.y * (double)qa.y;
      a += (double)rA.z * (double)qa.z;
      a += (double)rA.w * (double)qa.w;
      a += (double)rB.x * (double)qb.x;
      a += (double)rB.y * (double)qb.y;
      a += (double)rB.z * (double)qb.z;
      a += (double)rB.w * (double)qb.w;
#pragma unroll
      for (int m = 1; m < 64; m <<= 1) a += __shfl_xor(a, m, 64);
      dd[e] = a;
    }
    int i0 = 0; double u0d = dd[0];
#pragma unroll
    for (int e = 1; e < NE; ++e) { if (dd[e] > u0d) { u0d = dd[e]; i0 = e; } }
    int i1 = -1; double u1d = -1.0e300;
#pragma unroll
    for (int e = 0; e < NE; ++e) { if (e != i0 && dd[e] > u1d) { u1d = dd[e]; i1 = e; } }
    float u[NE]; float psum = 0.f;
#pragma unroll
    for (int e = 0; e < NE; ++e) { u[e] = __expf((float)(dd[e] - u0d)); psum += u[e]; }
    const float ua = (i0 == 0) ? u[0] : (i0 == 1) ? u[1] : (i0 == 2) ? u[2] : u[3];
    const float ub = (i1 == 0) ? u[0] : (i1 == 1) ? u[1] : (i1 == 2) ? u[2] : u[3];
    const float denom = ua + ub + 1e-20f * psum;
    if (lane == 0) {
      const int t = t0 + i;
      float2 idx2 = {(float)i0, (float)i1};
      float2 wt2  = {ua / denom, ub / denom};
      *(float2*)(out + 2 * t) = idx2;
      *(float2*)(out + 2 * TT + 2 * t) = wt2;
    }
  }
  __syncthreads();

  // last block finalizes aux_loss (counter at ws[64], zeroed per launch)
  if (wv == 0) {
    unsigned old = 0;
    if (lane == 0) old = atomicAdd((unsigned*)(ws + 64), 1u);
    old = __shfl((int)old, 0, 64);
    if (old == NBLK - 1) {
      const float val = atomicAdd(&ws[lane], 0.0f);   // fresh device-scope read
      const float oth = __shfl_xor(val, 4, 64);
      // lanes with (lane&4)==0: lane = b*8+e -> val=ssum(b,e), oth=cnt(b,e)
      float term = ((lane & 4) == 0) ? (oth / 4096.0f) * (val / 8192.0f) : 0.f;
#pragma unroll
      for (int m = 1; m < 64; m <<= 1) term += __shfl_xor(term, m, 64);
      if (lane == 0) out[4 * TT] = 0.1f * term / 8.0f;
    }
  }
}

extern "C" void kernel_launch(void* const* d_in, const int* in_sizes, int n_in,
                              void* d_out, int out_size, void* d_ws, size_t ws_size,
                              hipStream_t stream) {
  const float* x = (const float*)d_in[0];   // [8,8192,512] fp32
  const float* w = (const float*)d_in[1];   // [4,512] fp32
  float* out = (float*)d_out;               // idx[131072] | weight[131072] | aux[1]
  float* ws  = (float*)d_ws;                // [64] accum + [1] counter

  hipMemsetAsync(ws, 0, 512, stream);
  moe_gate_fused<<<NBLK, 256, 0, stream>>>(x, w, out, ws);
}

// Round 10
// 631.135 us; speedup vs baseline: 1.0959x; 1.0045x over previous
//
#include <hip/hip_runtime.h>

#define TT 65536          // total tokens = 8 * 8192
#define HDIM 512
#define NE 4
#define SEQL 8192
#define TPW 8             // tokens per wave
#define TPB 32            // tokens per block (4 waves)
#define NBLK (TT / TPB)   // 2048 blocks
#define EPS 1e-3f         // ~30x the fp32 split-dot error bound

// Wave-per-token, NATURAL register allocation (no min-waves bound).
// R8/R9 post-mortem: __launch_bounds__(256,8)'s 64-VGPR cap cannot hold the
// ~75-reg live set -> allocator collapsed to 32 VGPR + hot-loop scratch spill
// (WRITE_SIZE 41-80 MB, 17-19x regression). 4 waves/SIMD with zero spill is
// the verified operating point (R2/R3: 36.6 us).
// Kept from R9 (correctness-verified): LDS float4 weights (8 ds_read_b128
// per token, conflict-free), riskmask + post-loop fp64 fixup (~0.2% tokens,
// preserves exact np-float64 top-k ordering), fused aux via device atomics
// + last-block finalize.
__global__ __launch_bounds__(256) void moe_gate_fused(
    const float* __restrict__ x, const float* __restrict__ w,
    float* __restrict__ out, float* __restrict__ ws)
{
  const int tid  = threadIdx.x;
  const int lane = tid & 63;
  const int wv   = tid >> 6;
  const int b0 = lane & 1;
  const int b1 = (lane >> 1) & 1;

  __shared__ float4 wlds[NE * 2 * 64];   // [e][half][lane], 8 KB

  // stage weights: wave wv = expert wv; lane's chunk = {4l..4l+3} u {256+4l..+3}
  {
    const float4 a = *(const float4*)(w + wv * HDIM + 4 * lane);
    const float4 b = *(const float4*)(w + wv * HDIM + 256 + 4 * lane);
    wlds[(wv * 2 + 0) * 64 + lane] = a;
    wlds[(wv * 2 + 1) * 64 + lane] = b;
  }
  __syncthreads();
  const float4* wl = wlds + lane;        // single vaddr; (e*2+h)*64 folds to imm offset

  float ssum[NE] = {0.f, 0.f, 0.f, 0.f};
  float cnt[NE]  = {0.f, 0.f, 0.f, 0.f};
  unsigned riskmask = 0u;

  const int t0 = blockIdx.x * TPB + wv * TPW;
  const float4* xp = (const float4*)x;
  const size_t base = (size_t)t0 * (HDIM / 4);

  float4 cA = xp[base + lane];          // floats 4l..4l+3
  float4 cB = xp[base + 64 + lane];     // floats 256+4l..+3

  for (int i = 0; i < TPW; ++i) {
    float4 nA, nB;
    if (i + 1 < TPW) {
      const size_t nb = base + (size_t)(i + 1) * (HDIM / 4);
      nA = xp[nb + lane];
      nB = xp[nb + 64 + lane];
    }

    // per-lane fp32 partials; weights via 8 conflict-free ds_read_b128
    float pe[NE];
#pragma unroll
    for (int e = 0; e < NE; ++e) {
      const float4 qa = wl[(e * 2 + 0) * 64];
      const float4 qb = wl[(e * 2 + 1) * 64];
      float s = cA.x * qa.x;
      s = fmaf(cA.y, qa.y, s);
      s = fmaf(cA.z, qa.z, s);
      s = fmaf(cA.w, qa.w, s);
      s = fmaf(cB.x, qb.x, s);
      s = fmaf(cB.y, qb.y, s);
      s = fmaf(cB.z, qb.z, s);
      s = fmaf(cB.w, qb.w, s);
      pe[e] = s;
    }

    // reduce-scatter (masks 1,2) -> tree (4..32) -> allgather (1,2,3)  [R3-verified]
    const float s0 = (b0 ? pe[2] : pe[0]) + __shfl_xor(b0 ? pe[0] : pe[2], 1, 64);
    const float s1 = (b0 ? pe[3] : pe[1]) + __shfl_xor(b0 ? pe[1] : pe[3], 1, 64);
    float v = (b1 ? s1 : s0) + __shfl_xor(b1 ? s0 : s1, 2, 64);
    v += __shfl_xor(v, 4, 64);
    v += __shfl_xor(v, 8, 64);
    v += __shfl_xor(v, 16, 64);
    v += __shfl_xor(v, 32, 64);
    const float T2 = __shfl_xor(v, 1, 64);
    const float T1 = __shfl_xor(v, 2, 64);
    const float T3 = __shfl_xor(v, 3, 64);

    float acc[NE];
    acc[0] = b0 ? (b1 ? T3 : T2) : (b1 ? T1 : v);
    acc[1] = b0 ? (b1 ? T2 : T3) : (b1 ? v  : T1);
    acc[2] = b0 ? (b1 ? T1 : v)  : (b1 ? T3 : T2);
    acc[3] = b0 ? (b1 ? v  : T1) : (b1 ? T2 : T3);

    // top-1/2/3; strict '>' ascending = lowest-index tie-break
    int i0 = 0; float v0 = acc[0];
#pragma unroll
    for (int e = 1; e < NE; ++e) { if (acc[e] > v0) { v0 = acc[e]; i0 = e; } }
    int i1 = -1; float v1 = -3.4e38f;
#pragma unroll
    for (int e = 0; e < NE; ++e) { if (e != i0 && acc[e] > v1) { v1 = acc[e]; i1 = e; } }
    float v2 = -3.4e38f;
#pragma unroll
    for (int e = 0; e < NE; ++e) { if (e != i0 && e != i1 && acc[e] > v2) v2 = acc[e]; }

    // near-tie? just flag it (fp64 handled POST-LOOP; keeps hot loop lean)
    const int risky = ((v0 - v1) < EPS) | ((v1 - v2) < EPS);
    riskmask |= ((unsigned)__builtin_amdgcn_readfirstlane(risky)) << i;

    // softmax (fp32)
    float u[NE]; float psum = 0.f;
#pragma unroll
    for (int e = 0; e < NE; ++e) { u[e] = __expf(acc[e] - v0); psum += u[e]; }
    const float inv = 1.0f / psum;
#pragma unroll
    for (int e = 0; e < NE; ++e) {
      ssum[e] += u[e] * inv;
      cnt[e] += ((e == i0) ? 1.f : 0.f) + ((e == i1) ? 1.f : 0.f);
    }

    const float ua = (i0 == 0) ? u[0] : (i0 == 1) ? u[1] : (i0 == 2) ? u[2] : u[3];
    const float ub = (i1 == 0) ? u[0] : (i1 == 1) ? u[1] : (i1 == 2) ? u[2] : u[3];
    const float denom = ua + ub + 1e-20f * psum;   // == (p0+p1+1e-20)*psum
    const float wt0 = ua / denom, wt1 = ub / denom;

    if (lane == 0) {
      const int t = t0 + i;
      float2 idx2 = {(float)i0, (float)i1};
      float2 wt2  = {wt0, wt1};
      *(float2*)(out + 2 * t) = idx2;
      *(float2*)(out + 2 * TT + 2 * t) = wt2;
    }
    cA = nA; cB = nB;
  }

  // fused aux: lane 0's ssum/cnt ARE the wave totals (all lanes identical)
  if (lane == 0) {
    const int batch = blockIdx.x >> 8;     // 256 blocks per batch
#pragma unroll
    for (int k = 0; k < NE; ++k) {
      atomicAdd(&ws[batch * 8 + k], ssum[k]);
      atomicAdd(&ws[batch * 8 + 4 + k], cnt[k]);
    }
    __threadfence();
  }

  // post-loop fp64 fixup of flagged tokens (~0.2% of waves enter)
  while (riskmask) {
    const int i = __builtin_ctz(riskmask);
    riskmask &= riskmask - 1;
    const size_t rb = base + (size_t)i * (HDIM / 4);
    const float4 rA = xp[rb + lane];
    const float4 rB = xp[rb + 64 + lane];
    double dd[NE];
#pragma unroll
    for (int e = 0; e < NE; ++e) {
      const float4 qa = wl[(e * 2 + 0) * 64];
      const float4 qb = wl[(e * 2 + 1) * 64];
      double a = (double)rA.x * (double)qa.x;
      a += (double)rA.y * (double)qa.y;
      a += (double)rA.z * (double)qa.z;
      a += (double)rA.w * (double)qa.w;
      a += (double)rB.x * (double)qb.x;
      a += (double)rB.y * (double)qb.y;
      a += (double)rB.z * (double)qb.z;
      a += (double)rB.w * (double)qb.w;
#pragma unroll
      for (int m = 1; m < 64; m <<= 1) a += __shfl_xor(a, m, 64);
      dd[e] = a;
    }
    int i0 = 0; double u0d = dd[0];
#pragma unroll
    for (int e = 1; e < NE; ++e) { if (dd[e] > u0d) { u0d = dd[e]; i0 = e; } }
    int i1 = -1; double u1d = -1.0e300;
#pragma unroll
    for (int e = 0; e < NE; ++e) { if (e != i0 && dd[e] > u1d) { u1d = dd[e]; i1 = e; } }
    float u[NE]; float psum = 0.f;
#pragma unroll
    for (int e = 0; e < NE; ++e) { u[e] = __expf((float)(dd[e] - u0d)); psum += u[e]; }
    const float ua = (i0 == 0) ? u[0] : (i0 == 1) ? u[1] : (i0 == 2) ? u[2] : u[3];
    const float ub = (i1 == 0) ? u[0] : (i1 == 1) ? u[1] : (i1 == 2) ? u[2] : u[3];
    const float denom = ua + ub + 1e-20f * psum;
    if (lane == 0) {
      const int t = t0 + i;
      float2 idx2 = {(float)i0, (float)i1};
      float2 wt2  = {ua / denom, ub / denom};
      *(float2*)(out + 2 * t) = idx2;
      *(float2*)(out + 2 * TT + 2 * t) = wt2;
    }
  }
  __syncthreads();

  // last block finalizes aux_loss (counter at ws[64], zeroed per launch)
  if (wv == 0) {
    unsigned old = 0;
    if (lane == 0) old = atomicAdd((unsigned*)(ws + 64), 1u);
    old = __shfl((int)old, 0, 64);
    if (old == NBLK - 1) {
      const float val = atomicAdd(&ws[lane], 0.0f);   // fresh device-scope read
      const float oth = __shfl_xor(val, 4, 64);
      // lanes with (lane&4)==0: lane = b*8+e -> val=ssum(b,e), oth=cnt(b,e)
      float term = ((lane & 4) == 0) ? (oth / 4096.0f) * (val / 8192.0f) : 0.f;
#pragma unroll
      for (int m = 1; m < 64; m <<= 1) term += __shfl_xor(term, m, 64);
      if (lane == 0) out[4 * TT] = 0.1f * term / 8.0f;
    }
  }
}

extern "C" void kernel_launch(void* const* d_in, const int* in_sizes, int n_in,
                              void* d_out, int out_size, void* d_ws, size_t ws_size,
                              hipStream_t stream) {
  const float* x = (const float*)d_in[0];   // [8,8192,512] fp32
  const float* w = (const float*)d_in[1];   // [4,512] fp32
  float* out = (float*)d_out;               // idx[131072] | weight[131072] | aux[1]
  float* ws  = (float*)d_ws;                // [64] accum + [1] counter

  hipMemsetAsync(ws, 0, 512, stream);
  moe_gate_fused<<<NBLK, 256, 0, stream>>>(x, w, out, ws);
}